// Round 5
// baseline (339.607 us; speedup 1.0000x reference)
//
#include <hip/hip_runtime.h>

// Backward (bilinear) warp: out[b,c,h,w] = bilinear_sample(input[b,c], w+flow_x, h+flow_y)
// Shapes: input [4,32,512,512] f32, flow [4,2,512,512] f32, out [4,32,512,512] f32.
//
// R7: R6's failure isolated the bottleneck: global_load_lds staging of 64KB
// runs at ~10 B/cyc/CU when sourced from L3 (exposed stage = 13K cyc in R6;
// two sibling blocks' stages serialized on the per-CU DMA). R5's 6.75K
// cyc/channel period == that stage time: R5 is DMA-rate-limited. GEMM gets
// 66 B/cyc from the same intrinsic only because its tiles are L2-hot.
// Fix: wave-parallel reg-staging (global_load_dwordx4 -> VGPR -> ds_write_b128)
//  - 16 waves x 4 outstanding 1KB wave-loads = 64KB MLP/CU; L3 latency hidden
//    under the full gather phase (double buffer preserved).
//  - per channel: loads(c+1) issue ; gather(c) ; stores(c) ; ds_write(c+1)
//    [compiler emits vmcnt(4): drains the 4 loads, leaves 4 stores in flight]
//    ; lgkmcnt(0) ; ONE s_barrier.  Stores never drained in-loop (R5 rule).
//  - geometry/apron/swizzle identical to R5 -> isolates the staging variable.

constexpr int B = 4, C = 32, H = 512, W = 512;
constexpr int HW = H * W;
constexpr int TILE = 64;
constexpr int APRON = 31;       // covers |flow| <= 31 (3.87 sigma of N(0,8))
constexpr int RH = 128;         // staged rows  (64 + 31 + 31 + 1, padded)
constexpr int RW = 128;         // staged cols (dwords): 64 + 32 + 31 + 1 = 128
constexpr int BUF = RH * RW;    // 16384 dwords = 64 KiB per buffer

__global__ __launch_bounds__(1024, 1) void warp_tile_kernel(
    const float* __restrict__ input,
    const float* __restrict__ flow,
    float* __restrict__ out)
{
    __shared__ float s[2 * BUF];          // 128 KiB, double-buffered

    // XCD-aware bijective swizzle (256 blocks % 8 XCDs == 0):
    // each XCD gets 32 consecutive logical tiles (shared aprons stay in L2).
    int bid0 = (int)blockIdx.x;
    int bid = (bid0 & 7) * 32 + (bid0 >> 3);

    int tx = bid & 7;                     // [b:4][ty:8][tx:8]
    int ty = (bid >> 3) & 7;
    int b  = bid >> 6;
    int tx0 = tx * TILE, ty0 = ty * TILE;

    // virtual region origin (may be out of image; staging sources are clamped
    // per-lane, and clamped/garbage cells are provably never gathered)
    int rx0 = tx0 - 32;                   // 32 keeps RW=128 & 16B alignment
    int ry0 = ty0 - APRON;

    int tid  = (int)threadIdx.x;
    int lane = tid & 63;
    int wv   = tid >> 6;                  // wave id 0..15
    int cl   = tid & 63;                  // output col within tile
    int rl   = tid >> 6;                  // output row group (rows rl + 16p)

    // ---- staging offsets ----
    // wave wv, issue i (0..3): 64 lanes x 16B = 1KB = region rows r, r+1
    // (r = 8*wv + 2*i). Global src: lanes 0..31 row r, lanes 32..63 row r+1,
    // cols 4*(lane&31).. +3. LDS dst: linear, dword 4*lane within the 2 rows.
    int soff[4];
    int sr[4];
    int ldst = 4 * lane;                  // dword offset within the 1KB span
    {
        int lrow = lane >> 5;                        // 0 or 1
        int lc   = (lane & 31) << 2;                 // 0..124
        int gcol = min(max(rx0 + lc, 0), W - 4);     // 16B-aligned, in-row
        #pragma unroll
        for (int i = 0; i < 4; ++i) {
            int r = 8 * wv + 2 * i;                  // wave-uniform
            sr[i] = r;
            int grow = min(max(ry0 + r + lrow, 0), H - 1);
            soff[i] = grow * W + gcol;
        }
    }

    // ---- per-pixel precompute (4 px/thread), reused across 32 channels ----
    float wa[4], wb_[4], wc_[4], wd_[4];
    int a0[4], a1[4];
    int opix0 = (ty0 + rl) * W + tx0 + cl;

    #pragma unroll
    for (int p = 0; p < 4; ++p) {
        int h = ty0 + rl + 16 * p;
        int w = tx0 + cl;
        int pix = h * W + w;
        float fx = flow[(b * 2 + 0) * HW + pix];
        float fy = flow[(b * 2 + 1) * HW + pix];
        float x = fminf(fmaxf((float)w + fx, 0.0f), (float)(W - 1));
        float y = fminf(fmaxf((float)h + fy, 0.0f), (float)(H - 1));
        float x0f = floorf(x), y0f = floorf(y);
        int x0 = (int)x0f, y0 = (int)y0f;
        int y1 = min(y0 + 1, H - 1);
        float dx = x - x0f, dy = y - y0f;
        // weights use UNCLAMPED x1f=x0f+1, y1f=y0f+1 (matches reference)
        wa[p]  = (1.f - dx) * (1.f - dy);
        wb_[p] = (1.f - dx) * dy;
        wc_[p] = dx * (1.f - dy);
        wd_[p] = dx * dy;
        int ax0 = x0 - rx0, ay0 = y0 - ry0, ay1 = y1 - ry0;
        // need ax0 in [0,RW-2] (reads ax0+1), ay0>=0, ay1<=RH-1
        bool inreg = (ax0 >= 0) && (ax0 <= RW - 2) && (ay0 >= 0) && (ay1 <= RH - 1);
        // at x0==x1 (image right edge) the +1 read hits a staged-garbage col,
        // but its weight wc==dx==0 -> harmless. Same at bottom edge for y.
        a0[p] = inreg ? (ay0 * RW + ax0) : -1;
        a1[p] = ay1 * RW + ax0;
    }

    const float* iplane = input + (size_t)b * C * HW;
    float* oplane = out + (size_t)b * C * HW;

    // reg-staging: issue 4 x global_load_dwordx4 (1KB/wave-instr)
    float4 st[4];
    auto stage_load = [&](int c) {
        const float* gc = iplane + (size_t)c * HW;
        #pragma unroll
        for (int i = 0; i < 4; ++i)
            st[i] = *(const float4*)(gc + soff[i]);
    };
    // write staged regs to LDS buffer (compiler inserts the vmcnt for st[])
    auto stage_write = [&](int buf) {
        #pragma unroll
        for (int i = 0; i < 4; ++i)
            *(float4*)(&s[buf * BUF + sr[i] * RW + ldst]) = st[i];
    };

    stage_load(0);
    stage_write(0);
    __syncthreads();   // prologue: drain writes + barrier (buffer 0 staged)

    for (int c = 0; c < C; ++c) {
        if (c + 1 < C) stage_load(c + 1);        // issue loads FIRST (MLP)
        __builtin_amdgcn_sched_barrier(0);       // pin issue before gather

        // ---- gather from LDS + FMA (results held in regs) ----
        int base = (c & 1) * BUF;
        float v[4];
        #pragma unroll
        for (int p = 0; p < 4; ++p) {
            if (a0[p] >= 0) {
                int i0 = base + a0[p], i1 = base + a1[p];
                float v00 = s[i0], v01 = s[i0 + 1];
                float v10 = s[i1], v11 = s[i1 + 1];
                v[p] = wa[p] * v00 + wc_[p] * v01 + wb_[p] * v10 + wd_[p] * v11;
            } else {
                // outlier (|flow|>APRON, P ~ 2e-4/px): recompute + global gather
                int h = ty0 + rl + 16 * p;
                int w = tx0 + cl;
                int pix = h * W + w;
                float fx = flow[(b * 2 + 0) * HW + pix];
                float fy = flow[(b * 2 + 1) * HW + pix];
                float x = fminf(fmaxf((float)w + fx, 0.0f), (float)(W - 1));
                float y = fminf(fmaxf((float)h + fy, 0.0f), (float)(H - 1));
                float x0f = floorf(x), y0f = floorf(y);
                int x0 = (int)x0f, y0 = (int)y0f;
                int x1 = min(x0 + 1, W - 1), y1 = min(y0 + 1, H - 1);
                float dx = x - x0f, dy = y - y0f;
                const float* pch = iplane + (size_t)c * HW;
                v[p] = (1.f - dx) * (1.f - dy) * pch[y0 * W + x0]
                     + (1.f - dx) * dy         * pch[y1 * W + x0]
                     + dx * (1.f - dy)         * pch[y0 * W + x1]
                     + dx * dy                 * pch[y1 * W + x1];
            }
        }

        float* oc = oplane + (size_t)c * HW;
        #pragma unroll
        for (int p = 0; p < 4; ++p)
            oc[opix0 + 16 * p * W] = v[p];       // stores issued BEFORE ds_write

        if (c + 1 < C) {
            // ds_write needs st[] -> compiler emits vmcnt(4): drains the 4
            // loads (and last channel's long-retired stores), leaves this
            // channel's 4 stores in flight.
            stage_write((c + 1) & 1);
            // WAR for buf^1 was ensured by last iteration's lgkm+barrier
            // (gather(c-1) reads were in VGPRs before that barrier).
            asm volatile("s_waitcnt lgkmcnt(0)" ::: "memory");
            __builtin_amdgcn_sched_barrier(0);
            __builtin_amdgcn_s_barrier();        // ds_writes visible to all
            __builtin_amdgcn_sched_barrier(0);
        }
    }
}

extern "C" void kernel_launch(void* const* d_in, const int* in_sizes, int n_in,
                              void* d_out, int out_size, void* d_ws, size_t ws_size,
                              hipStream_t stream) {
    const float* input = (const float*)d_in[0];
    const float* flow  = (const float*)d_in[1];
    float* out = (float*)d_out;

    int grid = B * (H / TILE) * (W / TILE);   // 256 blocks -> 1 per CU
    warp_tile_kernel<<<grid, 1024, 0, stream>>>(input, flow, out);
}

// Round 6
// 249.313 us; speedup vs baseline: 1.3622x; 1.3622x over previous
//
#include <hip/hip_runtime.h>

// Backward (bilinear) warp: out[b,c,h,w] = bilinear_sample(input[b,c], w+flow_x, h+flow_y)
// Shapes: input [4,32,512,512] f32, flow [4,2,512,512] f32, out [4,32,512,512] f32.
//
// R8: R5 structure (best: 90.2us) with 25% fewer staged cache lines.
// Model from R3/R5/R6: stage path = ~6.4 cyc per 64B line per CU
// (MSHR x latency wall on L2/L3 fills). R5 staged 1024 lines/channel ->
// 6.5K cyc = its whole period. Only lever: fewer lines.
//  - staged region 128x128 -> 109 full rows x 112 cols = 12288 dwords
//    = 768 lines (-25%). Double buffer = 96 KiB LDS.
//  - staging is FLAT-linear: 48 instrs x 1KB = 16 waves x 3; instr k writes
//    flat dwords [256k,256k+256); per-lane global src = (ry0+flat/112)*W +
//    rx0+flat%112 precomputed at setup (global_load_lds dst stays linear).
//  - apron: x in (-24,+24), y in (-22,+23) -> P(outlier) ~ 0.76%/px.
//    Fallback made near-free: global tap address precomputed at setup
//    (channel-invariant), packed into a0/a1 (a0 = -1-(dx1+2*dy1) encodes
//    clamp bits; a1 = y0*W+x0). MLP pass issues all fb loads before combine.
//  - sync per channel (R5 rule, unchanged): stage(c+1) ; gather ; lgkm(0) ;
//    stores ; vmcnt(4) ; s_barrier. FIFO [stage x3, fb xm, stores x4] ->
//    vmcnt(4) drains stage+fb, never stores.
//  - R7 lesson: no lambdas, no staged-value arrays (spill -> +506MB writes).

constexpr int B = 4, C = 32, H = 512, W = 512;
constexpr int HW = H * W;
constexpr int TILE = 64;
constexpr int RW = 112;          // staged cols (dwords); x apron -24..+23
constexpr int RHF = 109;         // full gatherable rows; y apron -22..+22
constexpr int BUFD = 12288;      // dwords/buffer = 48 instrs * 256 (109.7 rows)
constexpr int XAP = 24, YAP = 22;

typedef __attribute__((address_space(1))) const unsigned int gas_u32;
typedef __attribute__((address_space(3))) unsigned int las_u32;

__global__ __launch_bounds__(1024, 1) void warp_tile_kernel(
    const float* __restrict__ input,
    const float* __restrict__ flow,
    float* __restrict__ out)
{
    __shared__ float s[2 * BUFD];         // 96 KiB, double-buffered

    // XCD-aware bijective swizzle (256 blocks % 8 XCDs == 0)
    int bid0 = (int)blockIdx.x;
    int bid = (bid0 & 7) * 32 + (bid0 >> 3);

    int tx = bid & 7;                     // [b:4][ty:8][tx:8]
    int ty = (bid >> 3) & 7;
    int b  = bid >> 6;
    int tx0 = tx * TILE, ty0 = ty * TILE;

    int rx0 = tx0 - XAP;                  // mult of 4 (tx0 mult 64)
    int ry0 = ty0 - YAP;

    int tid  = (int)threadIdx.x;
    int lane = tid & 63;
    int wv   = tid >> 6;                  // wave id 0..15
    int cl   = tid & 63;                  // output col within tile
    int rl   = tid >> 6;                  // output row group (rows rl + 16p)

    // ---- staging offsets: wave wv, issue i (0..2), flat dword region addr ----
    int soff[3];                          // per-lane global dword offset
    int sbase[3];                         // wave-uniform LDS dword base
    {
        #pragma unroll
        for (int i = 0; i < 3; ++i) {
            int base_ = (wv * 3 + i) * 256;          // wave-uniform
            sbase[i] = base_;
            int flat = base_ + 4 * lane;             // per-lane, mult of 4
            int row = flat / RW;                     // const-div (setup only)
            int col = flat - row * RW;               // 0..108, mult of 4
            int grow = min(max(ry0 + row, 0), H - 1);
            int gcol = min(max(rx0 + col, 0), W - 4);
            soff[i] = grow * W + gcol;
        }
    }

    // ---- per-pixel precompute (4 px/thread), reused across 32 channels ----
    float wa[4], wb_[4], wc_[4], wd_[4];
    int a0[4], a1[4];
    int opix0 = (ty0 + rl) * W + tx0 + cl;

    #pragma unroll
    for (int p = 0; p < 4; ++p) {
        int h = ty0 + rl + 16 * p;
        int w = tx0 + cl;
        int pix = h * W + w;
        float fx = flow[(b * 2 + 0) * HW + pix];
        float fy = flow[(b * 2 + 1) * HW + pix];
        float x = fminf(fmaxf((float)w + fx, 0.0f), (float)(W - 1));
        float y = fminf(fmaxf((float)h + fy, 0.0f), (float)(H - 1));
        float x0f = floorf(x), y0f = floorf(y);
        int x0 = (int)x0f, y0 = (int)y0f;
        int x1 = min(x0 + 1, W - 1), y1 = min(y0 + 1, H - 1);
        float dx = x - x0f, dy = y - y0f;
        // weights use UNCLAMPED x1f=x0f+1, y1f=y0f+1 (matches reference)
        wa[p]  = (1.f - dx) * (1.f - dy);
        wb_[p] = (1.f - dx) * dy;
        wc_[p] = dx * (1.f - dy);
        wd_[p] = dx * dy;
        int ax0 = x0 - rx0, ay0 = y0 - ry0, ay1 = y1 - ry0;
        // in-region: ax0 in [0,110] (reads ax0+1 <= 111), ay0>=0, ay1<=108
        bool inreg = (ax0 >= 0) && (ax0 <= RW - 2) && (ay0 >= 0) && (ay1 <= RHF - 1);
        if (inreg) {
            // right/bottom image edge: +1 read hits staged garbage * weight 0
            a0[p] = ay0 * RW + ax0;
            a1[p] = ay1 * RW + ax0;
        } else {
            // encode global fallback (channel-invariant): clamp bits + offset
            a0[p] = -1 - ((x1 - x0) + 2 * (y1 - y0));   // -1..-4
            a1[p] = y0 * W + x0;                        // plane dword offset
        }
    }

    const float* iplane = input + (size_t)b * C * HW;
    float* oplane = out + (size_t)b * C * HW;

    // async stage of channel cc into buffer bb (3 x 1KB per wave; flat-linear)
    #define STAGE(cc, bb) do {                                          \
        const float* gc_ = iplane + (size_t)(cc) * HW;                  \
        _Pragma("unroll")                                               \
        for (int i_ = 0; i_ < 3; ++i_) {                                \
            __builtin_amdgcn_global_load_lds(                           \
                (gas_u32*)(gc_ + soff[i_]),                             \
                (las_u32*)(&s[(bb) * BUFD + sbase[i_]]),                \
                16, 0, 0);                                              \
        }                                                               \
    } while (0)

    STAGE(0, 0);
    __syncthreads();   // prologue: vmcnt(0) + barrier (buffer 0 fully staged)

    for (int c = 0; c < C; ++c) {
        if (c + 1 < C) STAGE(c + 1, (c + 1) & 1);   // async prefetch FIRST
        __builtin_amdgcn_sched_barrier(0);

        int base = (c & 1) * BUFD;
        const float* pch = iplane + (size_t)c * HW;

        // ---- fallback MLP pass: issue all outlier loads up front ----
        float f00[4], f01[4], f10[4], f11[4];
        #pragma unroll
        for (int p = 0; p < 4; ++p) {
            if (a0[p] < 0) {
                int e = -1 - a0[p];                  // dx1 = e&1, dy1 = e>>1
                int g00 = a1[p];
                int g01 = g00 + (e & 1);
                int g10 = g00 + ((e & 2) ? W : 0);
                int g11 = g10 + (e & 1);
                f00[p] = pch[g00];
                f01[p] = pch[g01];
                f10[p] = pch[g10];
                f11[p] = pch[g11];
            }
        }

        // ---- gather from LDS (or fb regs) + FMA ----
        float v[4];
        #pragma unroll
        for (int p = 0; p < 4; ++p) {
            float v00, v01, v10, v11;
            if (a0[p] >= 0) {
                int i0 = base + a0[p], i1 = base + a1[p];
                v00 = s[i0]; v01 = s[i0 + 1];
                v10 = s[i1]; v11 = s[i1 + 1];
            } else {
                v00 = f00[p]; v01 = f01[p];
                v10 = f10[p]; v11 = f11[p];
            }
            v[p] = wa[p] * v00 + wc_[p] * v01 + wb_[p] * v10 + wd_[p] * v11;
        }

        // all ds_reads of buf are in VGPRs -> WAR-safe for stage(c+2)
        asm volatile("s_waitcnt lgkmcnt(0)" ::: "memory");
        __builtin_amdgcn_sched_barrier(0);

        float* oc = oplane + (size_t)c * HW;
        #pragma unroll
        for (int p = 0; p < 4; ++p)
            oc[opix0 + 16 * p * W] = v[p];       // stores AFTER stage + fb loads

        if (c + 1 < C) {
            // drain the 3 stage loads + any fb loads (already consumed);
            // leave this channel's 4 stores in flight
            asm volatile("s_waitcnt vmcnt(4)" ::: "memory");
            __builtin_amdgcn_sched_barrier(0);
            __builtin_amdgcn_s_barrier();        // RAW buf^1 staged; WAR buf read
            __builtin_amdgcn_sched_barrier(0);
        }
    }
    #undef STAGE
}

extern "C" void kernel_launch(void* const* d_in, const int* in_sizes, int n_in,
                              void* d_out, int out_size, void* d_ws, size_t ws_size,
                              hipStream_t stream) {
    const float* input = (const float*)d_in[0];
    const float* flow  = (const float*)d_in[1];
    float* out = (float*)d_out;

    int grid = B * (H / TILE) * (W / TILE);   // 256 blocks -> 1 per CU
    warp_tile_kernel<<<grid, 1024, 0, stream>>>(input, flow, out);
}